// Round 6
// baseline (53.642 us; speedup 1.0000x reference)
//
#include <hip/hip_runtime.h>
#include <hip/hip_fp16.h>

// Problem constants (match reference)
#define NRAYS 1048576
#define NV 32
#define ND 32
#define NF 6
#define NK 13        // 2F+1
#define SEG_CAP 36864  // 32768 expected + 23 sigma margin

typedef _Float16 h2 __attribute__((ext_vector_type(2)));
typedef float f4 __attribute__((ext_vector_type(4)));

__device__ __forceinline__ float fdot2acc(h2 a, h2 b, float c) {
#if __has_builtin(__builtin_amdgcn_fdot2)
    return __builtin_amdgcn_fdot2(a, b, c, false);
#else
    return c + (float)a.x * (float)b.x + (float)a.y * (float)b.y;
#endif
}

__device__ __forceinline__ h2 pack2(float a, float b) {
#if __has_builtin(__builtin_amdgcn_cvt_pkrtz)
    return __builtin_bit_cast(h2, __builtin_amdgcn_cvt_pkrtz(a, b));
#else
    h2 r; r.x = (_Float16)a; r.y = (_Float16)b; return r;
#endif
}

__device__ __forceinline__ float hwsin(float rev) {
#if __has_builtin(__builtin_amdgcn_sinf)
    return __builtin_amdgcn_sinf(rev);
#else
    return __sinf(6.28318530717958647692f * rev);
#endif
}
__device__ __forceinline__ float hwcos(float rev) {
#if __has_builtin(__builtin_amdgcn_cosf)
    return __builtin_amdgcn_cosf(rev);
#else
    return __cosf(6.28318530717958647692f * rev);
#endif
}

// ---------------------------------------------------------------------------
// K1: bucket rays by vid. Block-local LDS histogram -> one global atomicAdd
// per (block, v) -> per-ray rank via a second LDS-atomic round -> scatter
// (t, ray) records into per-vid segments. Output values are placement-order
// independent, so atomics keep the result deterministic.
__global__ __launch_bounds__(256) void scatter_kernel(
    const float* __restrict__ times,
    const int* __restrict__ vids,
    int* __restrict__ cursors,   // [32], zeroed via hipMemsetAsync
    uint2* __restrict__ recs)    // [32][SEG_CAP]
{
    __shared__ int hist[NV], hbase[NV], hist2[NV];
    const int tid = threadIdx.x;
    if (tid < NV) { hist[tid] = 0; hist2[tid] = 0; }
    __syncthreads();

    const int base = blockIdx.x * 1024;  // 1024 blocks * 1024 rays == NRAYS
    float t[4]; int v[4], r[4];
#pragma unroll
    for (int it = 0; it < 4; ++it) {
        r[it] = base + it * 256 + tid;
        t[it] = times[r[it]];
        v[it] = vids[r[it]];
        atomicAdd(&hist[v[it]], 1);
    }
    __syncthreads();
    if (tid < NV) hbase[tid] = atomicAdd(&cursors[tid], hist[tid]);
    __syncthreads();
#pragma unroll
    for (int it = 0; it < 4; ++it) {
        int rank = atomicAdd(&hist2[v[it]], 1);
        int slot = hbase[v[it]] + rank;
        if (slot < SEG_CAP) {
            uint2 rec;
            rec.x = __builtin_bit_cast(unsigned, t[it]);
            rec.y = (unsigned)r[it];
            recs[v[it] * SEG_CAP + slot] = rec;
        }
    }
}

// ---------------------------------------------------------------------------
// K2: each block serves ONE vid segment (48 blocks/segment). LDS holds only
// that vid's packed-f16 row (896 B). 8 threads per ray: thread q owns
// d = 4q..4q+3; ds_read_b128 at i*128 + q*16 is identical across the wave's
// 8 ray-groups -> same-address broadcast, zero bank conflicts.
// LDS dword j (0..223): i=j>>5, d=j&31 holds (w[d][2i], w[d][2i+1]) as h2.
__global__ __launch_bounds__(256, 6) void VideoEmbedding_kernel(
    const float* __restrict__ weights,
    const int* __restrict__ cursors,
    const uint2* __restrict__ recs,
    float* __restrict__ out)
{
    __shared__ _Float16 wl[7 * 64];  // 448 halves = 896 B

    const int tid = threadIdx.x;
    const int seg = blockIdx.x / 48;
    const int c = blockIdx.x % 48;

    if (tid < 224) {
        int i = tid >> 5, d = tid & 31;
        const float* wp = weights + seg * (ND * NK) + d * NK;
        float w0 = wp[2 * i];
        float w1 = (2 * i + 1 < NK) ? wp[2 * i + 1] : 0.f;
        reinterpret_cast<unsigned*>(wl)[tid] =
            __builtin_bit_cast(unsigned, pack2(w0, w1));
    }
    __syncthreads();

    const int count = min(cursors[seg], SEG_CAP);
    const uint2* srec = recs + seg * SEG_CAP;
    const int q = tid & 7;
    const int g = tid >> 3;  // ray-group 0..31 within block

    for (int r0 = c * 32; r0 < count; r0 += 48 * 32) {
        const int ridx = r0 + g;
        const bool valid = ridx < count;
        const uint2 rec = srec[valid ? ridx : count - 1];
        const float t = __builtin_bit_cast(float, rec.x);
        const int ray = (int)rec.y;

        // basis: s_j = sin(2^j pi t), c_j = cos(2^j pi t), j=0..5.
        // seed with HW trans (input in revolutions: 0.5t), then double-angle.
        float sv[NF], cv[NF];
        sv[0] = hwsin(0.5f * t);
        cv[0] = hwcos(0.5f * t);
#pragma unroll
        for (int j = 1; j < NF; ++j) {
            float sj = sv[j - 1], cj = cv[j - 1];
            sv[j] = 2.f * sj * cj;
            cv[j] = fmaf(-2.f * sj, sj, 1.f);
        }

        h2 bp[7];
        bp[0] = pack2(1.0f, sv[0]);
        bp[1] = pack2(sv[1], sv[2]);
        bp[2] = pack2(sv[3], sv[4]);
        bp[3] = pack2(sv[5], cv[0]);
        bp[4] = pack2(cv[1], cv[2]);
        bp[5] = pack2(cv[3], cv[4]);
        bp[6] = pack2(cv[5], 0.0f);  // pad half must be 0

        float a0 = 0.f, a1 = 0.f, a2 = 0.f, a3 = 0.f;
#pragma unroll
        for (int i = 0; i < 7; ++i) {
            uint4 w = *reinterpret_cast<const uint4*>(&wl[i * 64 + q * 8]);
            a0 = fdot2acc(__builtin_bit_cast(h2, w.x), bp[i], a0);
            a1 = fdot2acc(__builtin_bit_cast(h2, w.y), bp[i], a1);
            a2 = fdot2acc(__builtin_bit_cast(h2, w.z), bp[i], a2);
            a3 = fdot2acc(__builtin_bit_cast(h2, w.w), bp[i], a3);
        }

        if (valid) {
            f4 res;
            res.x = a0; res.y = a1; res.z = a2; res.w = a3;
            reinterpret_cast<f4*>(out)[(size_t)ray * 8 + q] = res;
        }
    }
}

extern "C" void kernel_launch(void* const* d_in, const int* in_sizes, int n_in,
                              void* d_out, int out_size, void* d_ws, size_t ws_size,
                              hipStream_t stream) {
    const float* times = (const float*)d_in[0];
    const int* vids = (const int*)d_in[1];
    const float* weights = (const float*)d_in[2];
    float* out = (float*)d_out;

    int* cursors = (int*)d_ws;
    uint2* recs = (uint2*)((char*)d_ws + 4096);

    hipMemsetAsync(d_ws, 0, 128, stream);
    hipLaunchKernelGGL(scatter_kernel, dim3(1024), dim3(256), 0, stream,
                       times, vids, cursors, recs);
    hipLaunchKernelGGL(VideoEmbedding_kernel, dim3(32 * 48), dim3(256), 0, stream,
                       weights, cursors, recs, out);
}

// Round 7
// 36.181 us; speedup vs baseline: 1.4826x; 1.4826x over previous
//
#include <hip/hip_runtime.h>
#include <hip/hip_fp16.h>

// Problem constants (match reference)
#define NRAYS 1048576
#define NV 32
#define ND 32
#define NF 6
#define NK 13  // 2F+1

typedef _Float16 h2 __attribute__((ext_vector_type(2)));
typedef float f4 __attribute__((ext_vector_type(4)));

__device__ __forceinline__ float fdot2acc(h2 a, h2 b, float c) {
#if __has_builtin(__builtin_amdgcn_fdot2)
    return __builtin_amdgcn_fdot2(a, b, c, false);
#else
    return c + (float)a.x * (float)b.x + (float)a.y * (float)b.y;
#endif
}

__device__ __forceinline__ h2 pack2(float a, float b) {
#if __has_builtin(__builtin_amdgcn_cvt_pkrtz)
    return __builtin_bit_cast(h2, __builtin_amdgcn_cvt_pkrtz(a, b));
#else
    h2 r; r.x = (_Float16)a; r.y = (_Float16)b; return r;
#endif
}

__device__ __forceinline__ float hwsin(float rev) {
#if __has_builtin(__builtin_amdgcn_sinf)
    return __builtin_amdgcn_sinf(rev);
#else
    return __sinf(6.28318530717958647692f * rev);
#endif
}
__device__ __forceinline__ float hwcos(float rev) {
#if __has_builtin(__builtin_amdgcn_cosf)
    return __builtin_amdgcn_cosf(rev);
#else
    return __cosf(6.28318530717958647692f * rev);
#endif
}

// ---------------------------------------------------------------------------
// Kernel A: pack f32 weights [V][D][K] into the f16 image in d_ws, with the
// d-quad chunks XOR-swizzled by (v&7) inside each 128B row.
// Image (dwords): idx = v*224 + i*32 + pos*4 + e; chunk at `pos` holds
// d-quad q = pos ^ (v&7); dword e -> d = 4q+e, halves (k=2i, 2i+1).
__global__ void pack_weights_kernel(const float* __restrict__ weights,
                                    unsigned* __restrict__ wpack)
{
    int j = blockIdx.x * 256 + threadIdx.x;  // 0 .. 7167 (dwords)
    if (j >= NV * 7 * 32) return;
    int v = j / 224;
    int r = j - v * 224;
    int i = r >> 5;          // k-pair 0..6
    int c = r & 31;          // dword within 128B row
    int pos = c >> 2;        // chunk position 0..7
    int e = c & 3;           // dword within chunk
    int q = pos ^ (v & 7);   // d-quad stored at this position
    int d = 4 * q + e;
    float w0 = weights[v * (ND * NK) + d * NK + 2 * i];
    float w1 = (2 * i + 1 < NK) ? weights[v * (ND * NK) + d * NK + 2 * i + 1] : 0.f;
    h2 p = pack2(w0, w1);
    wpack[j] = __builtin_bit_cast(unsigned, p);
}

// ---------------------------------------------------------------------------
// Main kernel. 8 threads per ray: thread q owns d = 4q..4q+3.
// 2 rays per thread per iteration (MLP: 14 ds_read_b128 + 2 nt-stores in
// flight), pair-ahead prefetch of (t, vid).
__global__ __launch_bounds__(256, 5) void VideoEmbedding_kernel(
    const float* __restrict__ times,
    const int* __restrict__ vids,
    const unsigned* __restrict__ wpack,
    float* __restrict__ out)
{
    __shared__ _Float16 wl[NV * 7 * ND * 2];  // 28672 B -> 5 blocks/CU

    const int tid = threadIdx.x;

    // Stage the pre-packed image: 7 x uint4 per thread, fully coalesced.
    {
        const uint4* src = reinterpret_cast<const uint4*>(wpack);
        uint4* dst = reinterpret_cast<uint4*>(wl);
#pragma unroll
        for (int j = 0; j < 7; ++j)
            dst[tid + j * 256] = src[tid + j * 256];
    }
    __syncthreads();

    const int q = tid & 7;
    const int gstride = (gridDim.x * 256) >> 3;  // total ray-groups = 40960
    int ray = ((blockIdx.x * 256) + tid) >> 3;

    // prefetch current pair
    float tt0 = times[ray];
    int vv0 = vids[ray];
    int r1 = min(ray + gstride, NRAYS - 1);
    float tt1 = times[r1];
    int vv1 = vids[r1];

    while (ray < NRAYS) {
        const int rayB = ray + gstride;
        // prefetch next pair (clamped loads; values unused on tail)
        const int rn0 = min(ray + 2 * gstride, NRAYS - 1);
        const int rn1 = min(ray + 3 * gstride, NRAYS - 1);
        const float tn0 = times[rn0], tn1 = times[rn1];
        const int vn0 = vids[rn0], vn1 = vids[rn1];

        const float tt[2] = {tt0, tt1};
        const int vv[2] = {vv0, vv1};
        f4 res[2];
#pragma unroll
        for (int u = 0; u < 2; ++u) {
            // basis: s_j = sin(2^j pi t), c_j = cos(2^j pi t); seed with HW
            // trans (input in revolutions: 0.5t), then double-angle chain.
            float sv[NF], cv[NF];
            sv[0] = hwsin(0.5f * tt[u]);
            cv[0] = hwcos(0.5f * tt[u]);
#pragma unroll
            for (int j = 1; j < NF; ++j) {
                float sj = sv[j - 1], cj = cv[j - 1];
                sv[j] = 2.f * sj * cj;
                cv[j] = fmaf(-2.f * sj, sj, 1.f);
            }

            h2 bp[7];
            bp[0] = pack2(1.0f, sv[0]);
            bp[1] = pack2(sv[1], sv[2]);
            bp[2] = pack2(sv[3], sv[4]);
            bp[3] = pack2(sv[5], cv[0]);
            bp[4] = pack2(cv[1], cv[2]);
            bp[5] = pack2(cv[3], cv[4]);
            bp[6] = pack2(cv[5], 0.0f);  // pad half must be 0

            const unsigned pos = (unsigned)(q ^ (vv[u] & 7));
            const unsigned base = (unsigned)vv[u] * 448u + pos * 8u;  // half idx
            float a0 = 0.f, a1 = 0.f, a2 = 0.f, a3 = 0.f;
#pragma unroll
            for (int i = 0; i < 7; ++i) {
                uint4 w = *reinterpret_cast<const uint4*>(&wl[base + i * 64]);
                a0 = fdot2acc(__builtin_bit_cast(h2, w.x), bp[i], a0);
                a1 = fdot2acc(__builtin_bit_cast(h2, w.y), bp[i], a1);
                a2 = fdot2acc(__builtin_bit_cast(h2, w.z), bp[i], a2);
                a3 = fdot2acc(__builtin_bit_cast(h2, w.w), bp[i], a3);
            }
            res[u].x = a0; res[u].y = a1; res[u].z = a2; res[u].w = a3;
        }

        __builtin_nontemporal_store(res[0],
            reinterpret_cast<f4*>(out) + (size_t)ray * 8 + q);
        if (rayB < NRAYS)
            __builtin_nontemporal_store(res[1],
                reinterpret_cast<f4*>(out) + (size_t)rayB * 8 + q);

        ray += 2 * gstride;
        tt0 = tn0; vv0 = vn0;
        tt1 = tn1; vv1 = vn1;
    }
}

extern "C" void kernel_launch(void* const* d_in, const int* in_sizes, int n_in,
                              void* d_out, int out_size, void* d_ws, size_t ws_size,
                              hipStream_t stream) {
    const float* times = (const float*)d_in[0];
    const int* vids = (const int*)d_in[1];
    const float* weights = (const float*)d_in[2];
    float* out = (float*)d_out;
    unsigned* wpack = (unsigned*)d_ws;

    hipLaunchKernelGGL(pack_weights_kernel, dim3(28), dim3(256), 0, stream,
                       weights, wpack);
    // 1280 blocks = 5 blocks/CU (LDS-limited at 28672 B/block), grid-stride.
    hipLaunchKernelGGL(VideoEmbedding_kernel, dim3(1280), dim3(256), 0, stream,
                       times, vids, wpack, out);
}